// Round 20
// baseline (159.660 us; speedup 1.0000x reference)
//
#include <hip/hip_runtime.h>

// ---------------------------------------------------------------------------
// Attention3: B=8, NKV=1024, D0=256, D1=512, D2=1024, DH=64, H0=2, H2=8
// Round 19: attention reverted to R17 2-way key-split (R18's 4-way split
// regressed: VGPR 112->132 crossed the 128 occupancy boundary, combine
// overhead doubled). proj q2 restructured: one block per 16 rows covers all
// 512 cols (wave = 8 col-tiles) -> LN computed once (was 4x), MFMA density
// 8 MFMA / 9 loads per chunk (was 2/3). Bit-identical accumulation order.
// out_gemm fp16 / proj_q0 / layouts unchanged from R17 (verified 2.441e-4).
//
// ws layout (BYTE offsets):
//   Kf   [8][16][4][2][64][8] bf16 @ 0 MB   (1 MB)
//   Vf   [8][16][4][2][64][8] bf16 @ 1 MB   (1 MB)
//   Q0bf [16][4096][64] bf16 @ 2 MB   (8 MB)
//   Q2bf [64][256][64]  bf16 @ 10 MB  (2 MB)
//   Of   [8192][640]    fp16 @ 12 MB  (10.5 MB)
//   WtKV [128][512]     bf16 @ 34 MB
//   WtQ0 [128][256]     bf16 @ 35 MB
//   WtQ2 [512][1024]    bf16 @ 36 MB  (1 MB)
//   WtO  [512][640]     fp16 @ 37 MB
// ---------------------------------------------------------------------------

typedef __attribute__((ext_vector_type(8))) short bf16x8;
typedef __attribute__((ext_vector_type(8))) _Float16 f16x8;
typedef __attribute__((ext_vector_type(4))) float f32x4;

constexpr size_t OFFB_KBF  = 0;
constexpr size_t OFFB_VT   = (size_t)1 << 20;
constexpr size_t OFFB_Q0   = (size_t)2 << 20;
constexpr size_t OFFB_Q2   = (size_t)10 << 20;
constexpr size_t OFFB_OF   = (size_t)12 << 20;
constexpr size_t OFFB_WTKV = (size_t)34 << 20;
constexpr size_t OFFB_WTQ0 = (size_t)35 << 20;
constexpr size_t OFFB_WTQ2 = (size_t)36 << 20;
constexpr size_t OFFB_WTO  = (size_t)37 << 20;

__device__ __forceinline__ unsigned short f2bf(float f) {
    union { float f; unsigned int u; } x; x.f = f;
    const unsigned int r = x.u + 0x7fffu + ((x.u >> 16) & 1u);
    return (unsigned short)(r >> 16);
}
__device__ __forceinline__ unsigned short f2h(float f) {
    union { _Float16 h; unsigned short u; } x;
    x.h = (_Float16)f;
    return x.u;
}
__device__ __forceinline__ unsigned int cvtpk_bf16(float lo, float hi) {
    unsigned int r;
    asm("v_cvt_pk_bf16_f32 %0, %1, %2" : "=v"(r) : "v"(lo), "v"(hi));
    return r;
}
__device__ __forceinline__ float fexp2(float x) {
    float r;
    asm("v_exp_f32 %0, %1" : "=v"(r) : "v"(x));
    return r;
}
#define EXP2_SCALE 0.18033688011112042f

// ---------------- merged weight transpose+convert ---------------------------
template <int R, int C, bool F16>
__device__ __forceinline__ void transpose_w_body(
    int lbid, const float* __restrict__ W,
    unsigned short* __restrict__ D, float (*t)[33])
{
    const int tid = threadIdx.x;
    const int tx = tid & 31, ty = tid >> 5;
    const int bx = lbid % (C / 32);
    const int by = lbid / (C / 32);
    #pragma unroll
    for (int j = 0; j < 4; ++j) {
        const int r = ty + j * 8;
        t[r][tx] = W[(size_t)(by * 32 + r) * C + bx * 32 + tx];
    }
    __syncthreads();
    #pragma unroll
    for (int j = 0; j < 4; ++j) {
        const int r = ty + j * 8;
        const float v = t[tx][r];
        const size_t dst = (size_t)(bx * 32 + r) * R + by * 32 + tx;
        D[dst] = F16 ? f2h(v) : f2bf(v);
    }
}

__global__ __launch_bounds__(256) void transpose_all_k(
    const float* __restrict__ Wkv, const float* __restrict__ Wq0,
    const float* __restrict__ Wq2, const float* __restrict__ Wout,
    unsigned short* __restrict__ WtKV, unsigned short* __restrict__ WtQ0,
    unsigned short* __restrict__ WtQ2, unsigned short* __restrict__ WtO)
{
    __shared__ float t[32][33];
    const int b = blockIdx.x;
    if (b < 64)       transpose_w_body<512, 128, false>(b, Wkv, WtKV, t);
    else if (b < 96)  transpose_w_body<256, 128, false>(b - 64, Wq0, WtQ0, t);
    else if (b < 608) transpose_w_body<1024, 512, false>(b - 96, Wq2, WtQ2, t);
    else              transpose_w_body<640, 512, true>(b - 608, Wout, WtO, t);
}

// ---------------- LN + MFMA projection body (R14 math, NT col-tiles/wave) ---
// NT=2: block covers 128 cols (cb selects); NT=8: block covers 512 cols.
template <int D, int MODE, int NRB, int NT>
__device__ __forceinline__ void ln_proj_body(
    int lbid, const float* __restrict__ X, const float* __restrict__ G,
    const float* __restrict__ Bv, const unsigned short* __restrict__ Wt,
    unsigned short* __restrict__ O0, unsigned short* __restrict__ O1,
    unsigned int* xn)
{
    constexpr int NJ = D / 128;

    const int tid  = threadIdx.x;
    const int lane = tid & 63;
    const int w    = tid >> 6;
    const int lq   = lane & 15;
    const int lg   = lane >> 4;

    const int rb      = lbid % NRB;
    const int cb      = lbid / NRB;
    const int colbase = cb * (NT * 64) + w * (NT * 16);

    #pragma unroll
    for (int rr = 0; rr < 4; ++rr) {
        const int r = w * 4 + rr;
        const float* xp = X + ((size_t)rb * 16 + r) * D;
        float2 xv[NJ];
        float ps = 0.f, pq = 0.f;
        #pragma unroll
        for (int j = 0; j < NJ; ++j) {
            xv[j] = *(const float2*)&xp[2 * lane + 128 * j];
            ps += xv[j].x + xv[j].y;
            pq += xv[j].x * xv[j].x + xv[j].y * xv[j].y;
        }
        #pragma unroll
        for (int off = 32; off >= 1; off >>= 1) {
            ps += __shfl_xor(ps, off);
            pq += __shfl_xor(pq, off);
        }
        const float mu  = ps * (1.f / D);
        const float var = pq * (1.f / D) - mu * mu;
        const float rs  = rsqrtf(var + 1e-5f);
        #pragma unroll
        for (int j = 0; j < NJ; ++j) {
            const int i2 = 2 * lane + 128 * j;
            const float2 gv = *(const float2*)&G[i2];
            const float2 bv = *(const float2*)&Bv[i2];
            const float a = (xv[j].x - mu) * rs * gv.x + bv.x;
            const float c = (xv[j].y - mu) * rs * gv.y + bv.y;
            const int pi = lane + 64 * j;
            xn[r * (D / 2) + ((((pi >> 2) ^ (r & 7)) << 2) | (pi & 3))] =
                cvtpk_bf16(a, c);
        }
    }
    __syncthreads();

    const unsigned short* wp = Wt + (size_t)(colbase + lq) * D + lg * 8;
    f32x4 acc[NT];
    #pragma unroll
    for (int t = 0; t < NT; ++t) acc[t] = f32x4{0.f, 0.f, 0.f, 0.f};
    #pragma unroll 4
    for (int kk = 0; kk < D / 32; ++kk) {
        const int ch = (kk * 4 + lg) ^ (lq & 7);
        const bf16x8 xf = *(const bf16x8*)&xn[lq * (D / 2) + ch * 4];
        #pragma unroll
        for (int t = 0; t < NT; ++t) {
            const bf16x8 wf = *(const bf16x8*)(wp + (size_t)t * 16 * D + kk * 32);
            acc[t] = __builtin_amdgcn_mfma_f32_16x16x32_bf16(wf, xf, acc[t], 0, 0, 0);
        }
    }

    const long grow = (long)rb * 16 + lq;
    #pragma unroll
    for (int t = 0; t < NT; ++t) {
        #pragma unroll
        for (int r = 0; r < 4; ++r) {
            const int c = colbase + t * 16 + lg * 4 + r;
            const unsigned short a = f2bf(acc[t][r]);
            if constexpr (MODE == 0) {
                const long bb   = grow >> 10;
                const long keyb = grow & 1023;
                const long tt_  = keyb >> 6;
                if (c < 64) {
                    const int kt = (int)((keyb >> 4) & 3);
                    const int ch = c >> 5;
                    const int ln = (int)((keyb & 15) | (((c & 31) >> 3) << 4));
                    const int e  = c & 7;
                    O0[((((bb * 16 + tt_) * 4 + kt) * 2 + ch) * 64 + ln) * 8 + e] = a;
                } else {
                    const int dv = c - 64;
                    const int i  = dv >> 4;
                    const int ch = (int)((keyb & 63) >> 5);
                    const int ln = (int)((dv & 15) | (((keyb & 31) >> 3) << 4));
                    const int e  = (int)(keyb & 7);
                    O1[((((bb * 16 + tt_) * 4 + i) * 2 + ch) * 64 + ln) * 8 + e] = a;
                }
            } else if constexpr (MODE == 1) {
                const long b = grow >> 12;
                const long m = grow & 4095;
                const int  h = c >> 6, dd = c & 63;
                O0[(((b * 2 + h) << 12) + m) * 64 + dd] = a;
            } else {
                const long b = grow >> 8;
                const long m = grow & 255;
                const int  h = c >> 6, dd = c & 63;
                O0[(((b * 8 + h) << 8) + m) * 64 + dd] = a;
            }
        }
    }
}

// kv (D=512, NT=2, blocks [0,512)) + q2 (D=1024, NT=8, blocks [512,640))
__global__ __launch_bounds__(256) void proj_kvq2_k(
    const float* __restrict__ x1, const float* __restrict__ x2,
    const float* __restrict__ g1, const float* __restrict__ b1,
    const float* __restrict__ g2, const float* __restrict__ b2,
    const unsigned short* __restrict__ WtKV, const unsigned short* __restrict__ WtQ2,
    unsigned short* __restrict__ Kf, unsigned short* __restrict__ Vf,
    unsigned short* __restrict__ Q2bf)
{
    __shared__ unsigned int xn[8192];
    const int b = blockIdx.x;
    if (b < 512) ln_proj_body<512, 0, 512, 2>(b, x1, g1, b1, WtKV, Kf, Vf, xn);
    else         ln_proj_body<1024, 2, 128, 8>(b - 512, x2, g2, b2, WtQ2, Q2bf, nullptr, xn);
}

__global__ __launch_bounds__(256) void proj_q0_k(
    const float* __restrict__ x0,
    const float* __restrict__ g0, const float* __restrict__ b0,
    const unsigned short* __restrict__ WtQ0,
    unsigned short* __restrict__ Q0bf)
{
    __shared__ unsigned int xn[2048];
    ln_proj_body<256, 1, 2048, 2>(blockIdx.x, x0, g0, b0, WtQ0, Q0bf, nullptr, xn);
}

// ---------------- MFMA attention (fragment K/V, 2-way key-split, R17) -------
__device__ __forceinline__ void load_ktile(
    const unsigned short* __restrict__ kp, int t, bf16x8 (&kf)[8])
{
    const unsigned short* ktb = kp + (size_t)t * 8 * 512;
    #pragma unroll
    for (int kt = 0; kt < 4; ++kt) {
        kf[2 * kt]     = *(const bf16x8*)(ktb + (kt * 2 + 0) * 512);
        kf[2 * kt + 1] = *(const bf16x8*)(ktb + (kt * 2 + 1) * 512);
    }
}

__device__ __forceinline__ void process_tile(
    int t, const bf16x8 (&kf)[8],
    const unsigned short* __restrict__ vp,
    const bf16x8& qfA0, const bf16x8& qfA1,
    const bf16x8& qfB0, const bf16x8& qfB1,
    f32x4 (&otA)[4], f32x4 (&otB)[4], float& psA, float& psB,
    unsigned int (&pl)[2][16][32], int lq, int lg)
{
    const unsigned short* vtb = vp + (size_t)t * 8 * 512;
    bf16x8 vf[8];
    #pragma unroll
    for (int i = 0; i < 4; ++i) {
        vf[2 * i]     = *(const bf16x8*)(vtb + (i * 2 + 0) * 512);
        vf[2 * i + 1] = *(const bf16x8*)(vtb + (i * 2 + 1) * 512);
    }

    #pragma unroll
    for (int kt = 0; kt < 4; ++kt) {
        f32x4 sA = f32x4{0.f, 0.f, 0.f, 0.f};
        sA = __builtin_amdgcn_mfma_f32_16x16x32_bf16(kf[2 * kt], qfA0, sA, 0, 0, 0);
        sA = __builtin_amdgcn_mfma_f32_16x16x32_bf16(kf[2 * kt + 1], qfA1, sA, 0, 0, 0);
        f32x4 sB = f32x4{0.f, 0.f, 0.f, 0.f};
        sB = __builtin_amdgcn_mfma_f32_16x16x32_bf16(kf[2 * kt], qfB0, sB, 0, 0, 0);
        sB = __builtin_amdgcn_mfma_f32_16x16x32_bf16(kf[2 * kt + 1], qfB1, sB, 0, 0, 0);

        float pA[4], pB[4];
        #pragma unroll
        for (int r = 0; r < 4; ++r) {
            pA[r] = fexp2(sA[r] * EXP2_SCALE);
            pB[r] = fexp2(sB[r] * EXP2_SCALE);
            psA += pA[r];
            psB += pB[r];
        }
        const int sw = (((2 * kt + (lg >> 1)) ^ (lq & 7)) << 2) | (2 * (lg & 1));
        pl[0][lq][sw]     = cvtpk_bf16(pA[0], pA[1]);
        pl[0][lq][sw + 1] = cvtpk_bf16(pA[2], pA[3]);
        pl[1][lq][sw]     = cvtpk_bf16(pB[0], pB[1]);
        pl[1][lq][sw + 1] = cvtpk_bf16(pB[2], pB[3]);
    }

    __builtin_amdgcn_s_setprio(1);
    #pragma unroll
    for (int k0g = 0; k0g < 2; ++k0g) {
        const int ch = k0g * 4 + lg;
        const bf16x8 pfA = *(const bf16x8*)&pl[0][lq][(ch ^ (lq & 7)) << 2];
        const bf16x8 pfB = *(const bf16x8*)&pl[1][lq][(ch ^ (lq & 7)) << 2];
        #pragma unroll
        for (int i = 0; i < 4; ++i) {
            otA[i] = __builtin_amdgcn_mfma_f32_16x16x32_bf16(vf[2 * i + k0g], pfA, otA[i], 0, 0, 0);
            otB[i] = __builtin_amdgcn_mfma_f32_16x16x32_bf16(vf[2 * i + k0g], pfB, otB[i], 0, 0, 0);
        }
    }
    __builtin_amdgcn_s_setprio(0);
}

template <int MODE>
__device__ __forceinline__ void attn_body(
    int lbid, const unsigned short* __restrict__ Q,
    const unsigned short* __restrict__ K,
    const unsigned short* __restrict__ Vt,
    unsigned short* __restrict__ Of,
    unsigned int (*plds)[2][16][32], float* __restrict__ psb)
{
    constexpr int H   = (MODE == 0) ? 2 : 8;
    constexpr int M   = (MODE == 0) ? 4096 : 256;
    constexpr int BPB = M / 64;

    const int tid  = threadIdx.x;
    const int lane = tid & 63;
    const int w    = tid >> 6;
    const int lq   = lane & 15;
    const int lg   = lane >> 4;

    const int bh  = lbid / BPB;
    const int qb  = lbid % BPB;
    const int qg  = w & 1;
    const int ks  = w >> 1;
    const int q0g = qb * 64 + qg * 32;
    const int b   = bh / H;
    const int h   = bh % H;

    const unsigned short* qpA = Q + ((size_t)bh * M + q0g + lq) * 64 + 8 * lg;
    const bf16x8 qfA0 = *(const bf16x8*)(qpA);
    const bf16x8 qfA1 = *(const bf16x8*)(qpA + 32);
    const bf16x8 qfB0 = *(const bf16x8*)(qpA + 16 * 64);
    const bf16x8 qfB1 = *(const bf16x8*)(qpA + 16 * 64 + 32);

    const unsigned short* kp = K  + (size_t)b * 65536 + 8 * lane;
    const unsigned short* vp = Vt + (size_t)b * 65536 + 8 * lane;

    f32x4 otA[4], otB[4];
    #pragma unroll
    for (int i = 0; i < 4; ++i) {
        otA[i] = f32x4{0.f, 0.f, 0.f, 0.f};
        otB[i] = f32x4{0.f, 0.f, 0.f, 0.f};
    }
    float psA = 0.f, psB = 0.f;

    const int tb = ks * 8;
    bf16x8 ka[8], kb[8];
    load_ktile(kp, tb, ka);

    #pragma unroll 1
    for (int tt = 0; tt < 4; ++tt) {
        load_ktile(kp, tb + 2 * tt + 1, kb);
        process_tile(tb + 2 * tt, ka, vp, qfA0, qfA1, qfB0, qfB1,
                     otA, otB, psA, psB, plds[w], lq, lg);
        if (tt < 3) load_ktile(kp, tb + 2 * tt + 2, ka);
        process_tile(tb + 2 * tt + 1, kb, vp, qfA0, qfA1, qfB0, qfB1,
                     otA, otB, psA, psB, plds[w], lq, lg);
    }

    __syncthreads();
    float* sc = (float*)plds;
    if (w >= 2) {
        const int off = (w - 2) * 64 + lane;
        #pragma unroll
        for (int i = 0; i < 4; ++i) {
            #pragma unroll
            for (int r = 0; r < 4; ++r) {
                sc[(i * 4 + r) * 128 + off]        = otA[i][r];
                sc[(16 + i * 4 + r) * 128 + off]   = otB[i][r];
            }
        }
        psb[off]       = psA;
        psb[128 + off] = psB;
    }
    __syncthreads();
    if (w < 2) {
        const int off = w * 64 + lane;
        #pragma unroll
        for (int i = 0; i < 4; ++i) {
            #pragma unroll
            for (int r = 0; r < 4; ++r) {
                otA[i][r] += sc[(i * 4 + r) * 128 + off];
                otB[i][r] += sc[(16 + i * 4 + r) * 128 + off];
            }
        }
        psA += psb[off];
        psB += psb[128 + off];

        psA += __shfl_xor(psA, 16); psA += __shfl_xor(psA, 32);
        psB += __shfl_xor(psB, 16); psB += __shfl_xor(psB, 32);
        const float invA = 1.f / psA;
        const float invB = 1.f / psB;

        #pragma unroll
        for (int half = 0; half < 2; ++half) {
            const int   m   = q0g + half * 16 + lq;
            const float inv = half ? invB : invA;
            #pragma unroll
            for (int i = 0; i < 4; ++i) {
                #pragma unroll
                for (int r = 0; r < 4; ++r) {
                    const int   dv  = i * 16 + lg * 4 + r;
                    const float val = (half ? otB[i][r] : otA[i][r]) * inv;
                    size_t dst;
                    if constexpr (MODE == 0) {
                        dst = ((size_t)b * 1024 + (m >> 2)) * 640 + h * 320 + (m & 3) * 64 + dv;
                    } else {
                        dst = ((size_t)b * 1024 + ((h & 3) * 256 + m)) * 640 + (h >> 2) * 320 + 256 + dv;
                    }
                    Of[dst] = f2h(val);
                }
            }
        }
    }
}

__global__ __launch_bounds__(256) void attn_all_k(
    const unsigned short* __restrict__ Q0, const unsigned short* __restrict__ Q2,
    const unsigned short* __restrict__ K, const unsigned short* __restrict__ Vt,
    unsigned short* __restrict__ Of)
{
    __shared__ unsigned int plds[4][2][16][32];
    __shared__ float psb[256];
    if (blockIdx.x < 1024) attn_body<0>(blockIdx.x, Q0, K, Vt, Of, plds, psb);
    else                   attn_body<1>(blockIdx.x - 1024, Q2, K, Vt, Of, plds, psb);
}

// ---------------- final GEMM: single-pass fp16 MFMA, 64x128, 4 waves -------
__global__ __launch_bounds__(256) void out_gemm_f16_k(
    const unsigned short* __restrict__ Of, const unsigned short* __restrict__ WtO,
    float* __restrict__ OUT)
{
    const int tid  = threadIdx.x;
    const int lane = tid & 63;
    const int w    = tid >> 6;
    const int lq   = lane & 15;
    const int lg   = lane >> 4;

    const int bid = blockIdx.x;
    const int rp  = (bid & 7) + 8 * (bid >> 5);   // 0..127 row panel
    const int cb  = (bid >> 3) & 3;               // 0..3 col block

    const long row0    = (long)rp * 64;
    const int  colbase = cb * 128 + w * 32;

    const unsigned short* aP = Of  + (size_t)(row0 + lq) * 640 + lg * 8;
    const unsigned short* bP = WtO + (size_t)(colbase + lq) * 640 + lg * 8;

    f16x8 a0[4], b0[2], a1[4], b1[2];

    auto load0 = [&](int kk) {
        #pragma unroll
        for (int rt = 0; rt < 4; ++rt)
            a0[rt] = *(const f16x8*)(aP + (size_t)rt * 16 * 640 + kk * 32);
        #pragma unroll
        for (int ct = 0; ct < 2; ++ct)
            b0[ct] = *(const f16x8*)(bP + (size_t)ct * 16 * 640 + kk * 32);
    };
    auto load1 = [&](int kk) {
        #pragma unroll
        for (int rt = 0; rt < 4; ++rt)
            a1[rt] = *(const f16x8*)(aP + (size_t)rt * 16 * 640 + kk * 32);
        #pragma unroll
        for (int ct = 0; ct < 2; ++ct)
            b1[ct] = *(const f16x8*)(bP + (size_t)ct * 16 * 640 + kk * 32);
    };

    f32x4 acc[4][2];
    #pragma unroll
    for (int rt = 0; rt < 4; ++rt)
        #pragma unroll
        for (int ct = 0; ct < 2; ++ct) acc[rt][ct] = f32x4{0.f, 0.f, 0.f, 0.f};

    auto mma0 = [&]() {
        #pragma unroll
        for (int rt = 0; rt < 4; ++rt)
            #pragma unroll
            for (int ct = 0; ct < 2; ++ct)
                acc[rt][ct] = __builtin_amdgcn_mfma_f32_16x16x32_f16(a0[rt], b0[ct], acc[rt][ct], 0, 0, 0);
    };
    auto mma1 = [&]() {
        #pragma unroll
        for (int rt = 0; rt < 4; ++rt)
            #pragma unroll
            for (int ct = 0; ct < 2; ++ct)
                acc[rt][ct] = __builtin_amdgcn_mfma_f32_16x16x32_f16(a1[rt], b1[ct], acc[rt][ct], 0, 0, 0);
    };

    load0(0);
    #pragma unroll 1
    for (int kk2 = 0; kk2 < 10; ++kk2) {     // 20 K-chunks, 2 per iter
        load1(2 * kk2 + 1);
        mma0();
        if (kk2 < 9) load0(2 * kk2 + 2);
        mma1();
    }

    #pragma unroll
    for (int rt = 0; rt < 4; ++rt)
        #pragma unroll
        for (int ct = 0; ct < 2; ++ct)
            #pragma unroll
            for (int r = 0; r < 4; ++r)
                OUT[(size_t)(row0 + rt * 16 + lg * 4 + r) * 512
                    + colbase + ct * 16 + lq] = acc[rt][ct][r];
}

extern "C" void kernel_launch(void* const* d_in, const int* in_sizes, int n_in,
                              void* d_out, int out_size, void* d_ws, size_t ws_size,
                              hipStream_t stream) {
    const float* x0   = (const float*)d_in[0];
    const float* x1   = (const float*)d_in[1];
    const float* x2   = (const float*)d_in[2];
    const float* g0   = (const float*)d_in[3];
    const float* b0   = (const float*)d_in[4];
    const float* g1   = (const float*)d_in[5];
    const float* b1   = (const float*)d_in[6];
    const float* g2   = (const float*)d_in[7];
    const float* b2   = (const float*)d_in[8];
    const float* Wq0  = (const float*)d_in[9];
    const float* Wkv  = (const float*)d_in[10];
    const float* Wq2  = (const float*)d_in[11];
    const float* Wout = (const float*)d_in[12];
    float* out = (float*)d_out;

    char* wsb = (char*)d_ws;
    unsigned short* Kf   = (unsigned short*)(wsb + OFFB_KBF);
    unsigned short* Vf   = (unsigned short*)(wsb + OFFB_VT);
    unsigned short* Q0bf = (unsigned short*)(wsb + OFFB_Q0);
    unsigned short* Q2bf = (unsigned short*)(wsb + OFFB_Q2);
    unsigned short* Of   = (unsigned short*)(wsb + OFFB_OF);
    unsigned short* WtKV = (unsigned short*)(wsb + OFFB_WTKV);
    unsigned short* WtQ0 = (unsigned short*)(wsb + OFFB_WTQ0);
    unsigned short* WtQ2 = (unsigned short*)(wsb + OFFB_WTQ2);
    unsigned short* WtO  = (unsigned short*)(wsb + OFFB_WTO);

    transpose_all_k<<<928, 256, 0, stream>>>(Wkv, Wq0, Wq2, Wout,
                                             WtKV, WtQ0, WtQ2, WtO);
    proj_kvq2_k<<<640, 256, 0, stream>>>(x1, x2, g1, b1, g2, b2,
                                         WtKV, WtQ2, Kf, Vf, Q2bf);
    proj_q0_k<<<2048, 256, 0, stream>>>(x0, g0, b0, WtQ0, Q0bf);
    attn_all_k<<<1280, 256, 0, stream>>>(Q0bf, Q2bf, Kf, Vf, Of);
    out_gemm_f16_k<<<512, 256, 0, stream>>>(Of, WtO, out);
}

// Round 21
// 121.236 us; speedup vs baseline: 1.3169x; 1.3169x over previous
//
#include <hip/hip_runtime.h>

// ---------------------------------------------------------------------------
// Attention3: B=8, NKV=1024, D0=256, D1=512, D2=1024, DH=64, H0=2, H2=8
// Round 20: FULL REVERT to R17 (best known, 121.2 us, absmax 2.441e-4).
//  R18 (4-way key-split) regressed: VGPR 112->132 crossed occupancy boundary.
//  R19 (q2 NT=8 proj) regressed: 128 fat blocks -> half the CUs idle.
//  Both directions away from this balance lose; re-anchor here.
//
// ws layout (BYTE offsets):
//   Kf   [8][16][4][2][64][8] bf16 @ 0 MB   (1 MB)
//   Vf   [8][16][4][2][64][8] bf16 @ 1 MB   (1 MB)
//   Q0bf [16][4096][64] bf16 @ 2 MB   (8 MB)
//   Q2bf [64][256][64]  bf16 @ 10 MB  (2 MB)
//   Of   [8192][640]    fp16 @ 12 MB  (10.5 MB)
//   WtKV [128][512]     bf16 @ 34 MB
//   WtQ0 [128][256]     bf16 @ 35 MB
//   WtQ2 [512][1024]    bf16 @ 36 MB  (1 MB)
//   WtO  [512][640]     fp16 @ 37 MB
// ---------------------------------------------------------------------------

typedef __attribute__((ext_vector_type(8))) short bf16x8;
typedef __attribute__((ext_vector_type(8))) _Float16 f16x8;
typedef __attribute__((ext_vector_type(4))) float f32x4;

constexpr size_t OFFB_KBF  = 0;
constexpr size_t OFFB_VT   = (size_t)1 << 20;
constexpr size_t OFFB_Q0   = (size_t)2 << 20;
constexpr size_t OFFB_Q2   = (size_t)10 << 20;
constexpr size_t OFFB_OF   = (size_t)12 << 20;
constexpr size_t OFFB_WTKV = (size_t)34 << 20;
constexpr size_t OFFB_WTQ0 = (size_t)35 << 20;
constexpr size_t OFFB_WTQ2 = (size_t)36 << 20;
constexpr size_t OFFB_WTO  = (size_t)37 << 20;

__device__ __forceinline__ unsigned short f2bf(float f) {
    union { float f; unsigned int u; } x; x.f = f;
    const unsigned int r = x.u + 0x7fffu + ((x.u >> 16) & 1u);
    return (unsigned short)(r >> 16);
}
__device__ __forceinline__ unsigned short f2h(float f) {
    union { _Float16 h; unsigned short u; } x;
    x.h = (_Float16)f;
    return x.u;
}
__device__ __forceinline__ unsigned int cvtpk_bf16(float lo, float hi) {
    unsigned int r;
    asm("v_cvt_pk_bf16_f32 %0, %1, %2" : "=v"(r) : "v"(lo), "v"(hi));
    return r;
}
__device__ __forceinline__ float fexp2(float x) {
    float r;
    asm("v_exp_f32 %0, %1" : "=v"(r) : "v"(x));
    return r;
}
#define EXP2_SCALE 0.18033688011112042f

// ---------------- merged weight transpose+convert ---------------------------
template <int R, int C, bool F16>
__device__ __forceinline__ void transpose_w_body(
    int lbid, const float* __restrict__ W,
    unsigned short* __restrict__ D, float (*t)[33])
{
    const int tid = threadIdx.x;
    const int tx = tid & 31, ty = tid >> 5;
    const int bx = lbid % (C / 32);
    const int by = lbid / (C / 32);
    #pragma unroll
    for (int j = 0; j < 4; ++j) {
        const int r = ty + j * 8;
        t[r][tx] = W[(size_t)(by * 32 + r) * C + bx * 32 + tx];
    }
    __syncthreads();
    #pragma unroll
    for (int j = 0; j < 4; ++j) {
        const int r = ty + j * 8;
        const float v = t[tx][r];
        const size_t dst = (size_t)(bx * 32 + r) * R + by * 32 + tx;
        D[dst] = F16 ? f2h(v) : f2bf(v);
    }
}

__global__ __launch_bounds__(256) void transpose_all_k(
    const float* __restrict__ Wkv, const float* __restrict__ Wq0,
    const float* __restrict__ Wq2, const float* __restrict__ Wout,
    unsigned short* __restrict__ WtKV, unsigned short* __restrict__ WtQ0,
    unsigned short* __restrict__ WtQ2, unsigned short* __restrict__ WtO)
{
    __shared__ float t[32][33];
    const int b = blockIdx.x;
    if (b < 64)       transpose_w_body<512, 128, false>(b, Wkv, WtKV, t);
    else if (b < 96)  transpose_w_body<256, 128, false>(b - 64, Wq0, WtQ0, t);
    else if (b < 608) transpose_w_body<1024, 512, false>(b - 96, Wq2, WtQ2, t);
    else              transpose_w_body<640, 512, true>(b - 608, Wout, WtO, t);
}

// ---------------- LN + MFMA projection body (verified R14 math) -------------
template <int D, int MODE, int NRB>
__device__ __forceinline__ void ln_proj_body(
    int lbid, const float* __restrict__ X, const float* __restrict__ G,
    const float* __restrict__ Bv, const unsigned short* __restrict__ Wt,
    unsigned short* __restrict__ O0, unsigned short* __restrict__ O1,
    unsigned int* xn)
{
    constexpr int NJ = D / 128;

    const int tid  = threadIdx.x;
    const int lane = tid & 63;
    const int w    = tid >> 6;
    const int lq   = lane & 15;
    const int lg   = lane >> 4;

    const int rb      = lbid % NRB;
    const int cb      = lbid / NRB;
    const int colbase = cb * 128 + w * 32;

    #pragma unroll
    for (int rr = 0; rr < 4; ++rr) {
        const int r = w * 4 + rr;
        const float* xp = X + ((size_t)rb * 16 + r) * D;
        float2 xv[NJ];
        float ps = 0.f, pq = 0.f;
        #pragma unroll
        for (int j = 0; j < NJ; ++j) {
            xv[j] = *(const float2*)&xp[2 * lane + 128 * j];
            ps += xv[j].x + xv[j].y;
            pq += xv[j].x * xv[j].x + xv[j].y * xv[j].y;
        }
        #pragma unroll
        for (int off = 32; off >= 1; off >>= 1) {
            ps += __shfl_xor(ps, off);
            pq += __shfl_xor(pq, off);
        }
        const float mu  = ps * (1.f / D);
        const float var = pq * (1.f / D) - mu * mu;
        const float rs  = rsqrtf(var + 1e-5f);
        #pragma unroll
        for (int j = 0; j < NJ; ++j) {
            const int i2 = 2 * lane + 128 * j;
            const float2 gv = *(const float2*)&G[i2];
            const float2 bv = *(const float2*)&Bv[i2];
            const float a = (xv[j].x - mu) * rs * gv.x + bv.x;
            const float c = (xv[j].y - mu) * rs * gv.y + bv.y;
            const int pi = lane + 64 * j;
            xn[r * (D / 2) + ((((pi >> 2) ^ (r & 7)) << 2) | (pi & 3))] =
                cvtpk_bf16(a, c);
        }
    }
    __syncthreads();

    const unsigned short* wp = Wt + (size_t)(colbase + lq) * D + lg * 8;
    f32x4 acc0 = f32x4{0.f, 0.f, 0.f, 0.f};
    f32x4 acc1 = f32x4{0.f, 0.f, 0.f, 0.f};
    #pragma unroll 4
    for (int kk = 0; kk < D / 32; ++kk) {
        const int ch = (kk * 4 + lg) ^ (lq & 7);
        const bf16x8 xf = *(const bf16x8*)&xn[lq * (D / 2) + ch * 4];
        const bf16x8 wf0 = *(const bf16x8*)(wp + kk * 32);
        const bf16x8 wf1 = *(const bf16x8*)(wp + 16 * D + kk * 32);
        acc0 = __builtin_amdgcn_mfma_f32_16x16x32_bf16(wf0, xf, acc0, 0, 0, 0);
        acc1 = __builtin_amdgcn_mfma_f32_16x16x32_bf16(wf1, xf, acc1, 0, 0, 0);
    }

    const long grow = (long)rb * 16 + lq;
    #pragma unroll
    for (int t = 0; t < 2; ++t) {
        const f32x4 acc = t ? acc1 : acc0;
        #pragma unroll
        for (int r = 0; r < 4; ++r) {
            const int c = colbase + t * 16 + lg * 4 + r;
            const unsigned short a = f2bf(acc[r]);
            if constexpr (MODE == 0) {
                const long bb   = grow >> 10;
                const long keyb = grow & 1023;
                const long tt_  = keyb >> 6;
                if (c < 64) {
                    const int kt = (int)((keyb >> 4) & 3);
                    const int ch = c >> 5;
                    const int ln = (int)((keyb & 15) | (((c & 31) >> 3) << 4));
                    const int e  = c & 7;
                    O0[((((bb * 16 + tt_) * 4 + kt) * 2 + ch) * 64 + ln) * 8 + e] = a;
                } else {
                    const int dv = c - 64;
                    const int i  = dv >> 4;
                    const int ch = (int)((keyb & 63) >> 5);
                    const int ln = (int)((dv & 15) | (((keyb & 31) >> 3) << 4));
                    const int e  = (int)(keyb & 7);
                    O1[((((bb * 16 + tt_) * 4 + i) * 2 + ch) * 64 + ln) * 8 + e] = a;
                }
            } else if constexpr (MODE == 1) {
                const long b = grow >> 12;
                const long m = grow & 4095;
                const int  h = c >> 6, dd = c & 63;
                O0[(((b * 2 + h) << 12) + m) * 64 + dd] = a;
            } else {
                const long b = grow >> 8;
                const long m = grow & 255;
                const int  h = c >> 6, dd = c & 63;
                O0[(((b * 8 + h) << 8) + m) * 64 + dd] = a;
            }
        }
    }
}

__global__ __launch_bounds__(256) void proj_kvq2_k(
    const float* __restrict__ x1, const float* __restrict__ x2,
    const float* __restrict__ g1, const float* __restrict__ b1,
    const float* __restrict__ g2, const float* __restrict__ b2,
    const unsigned short* __restrict__ WtKV, const unsigned short* __restrict__ WtQ2,
    unsigned short* __restrict__ Kf, unsigned short* __restrict__ Vf,
    unsigned short* __restrict__ Q2bf)
{
    __shared__ unsigned int xn[8192];
    const int b = blockIdx.x;
    if (b < 512) ln_proj_body<512, 0, 512>(b, x1, g1, b1, WtKV, Kf, Vf, xn);
    else         ln_proj_body<1024, 2, 128>(b - 512, x2, g2, b2, WtQ2, Q2bf, nullptr, xn);
}

__global__ __launch_bounds__(256) void proj_q0_k(
    const float* __restrict__ x0,
    const float* __restrict__ g0, const float* __restrict__ b0,
    const unsigned short* __restrict__ WtQ0,
    unsigned short* __restrict__ Q0bf)
{
    __shared__ unsigned int xn[2048];
    ln_proj_body<256, 1, 2048>(blockIdx.x, x0, g0, b0, WtQ0, Q0bf, nullptr, xn);
}

// ---------------- MFMA attention (fragment K/V, 2-way key-split) ------------
__device__ __forceinline__ void load_ktile(
    const unsigned short* __restrict__ kp, int t, bf16x8 (&kf)[8])
{
    const unsigned short* ktb = kp + (size_t)t * 8 * 512;
    #pragma unroll
    for (int kt = 0; kt < 4; ++kt) {
        kf[2 * kt]     = *(const bf16x8*)(ktb + (kt * 2 + 0) * 512);
        kf[2 * kt + 1] = *(const bf16x8*)(ktb + (kt * 2 + 1) * 512);
    }
}

__device__ __forceinline__ void process_tile(
    int t, const bf16x8 (&kf)[8],
    const unsigned short* __restrict__ vp,
    const bf16x8& qfA0, const bf16x8& qfA1,
    const bf16x8& qfB0, const bf16x8& qfB1,
    f32x4 (&otA)[4], f32x4 (&otB)[4], float& psA, float& psB,
    unsigned int (&pl)[2][16][32], int lq, int lg)
{
    const unsigned short* vtb = vp + (size_t)t * 8 * 512;
    bf16x8 vf[8];
    #pragma unroll
    for (int i = 0; i < 4; ++i) {
        vf[2 * i]     = *(const bf16x8*)(vtb + (i * 2 + 0) * 512);
        vf[2 * i + 1] = *(const bf16x8*)(vtb + (i * 2 + 1) * 512);
    }

    #pragma unroll
    for (int kt = 0; kt < 4; ++kt) {
        f32x4 sA = f32x4{0.f, 0.f, 0.f, 0.f};
        sA = __builtin_amdgcn_mfma_f32_16x16x32_bf16(kf[2 * kt], qfA0, sA, 0, 0, 0);
        sA = __builtin_amdgcn_mfma_f32_16x16x32_bf16(kf[2 * kt + 1], qfA1, sA, 0, 0, 0);
        f32x4 sB = f32x4{0.f, 0.f, 0.f, 0.f};
        sB = __builtin_amdgcn_mfma_f32_16x16x32_bf16(kf[2 * kt], qfB0, sB, 0, 0, 0);
        sB = __builtin_amdgcn_mfma_f32_16x16x32_bf16(kf[2 * kt + 1], qfB1, sB, 0, 0, 0);

        float pA[4], pB[4];
        #pragma unroll
        for (int r = 0; r < 4; ++r) {
            pA[r] = fexp2(sA[r] * EXP2_SCALE);
            pB[r] = fexp2(sB[r] * EXP2_SCALE);
            psA += pA[r];
            psB += pB[r];
        }
        const int sw = (((2 * kt + (lg >> 1)) ^ (lq & 7)) << 2) | (2 * (lg & 1));
        pl[0][lq][sw]     = cvtpk_bf16(pA[0], pA[1]);
        pl[0][lq][sw + 1] = cvtpk_bf16(pA[2], pA[3]);
        pl[1][lq][sw]     = cvtpk_bf16(pB[0], pB[1]);
        pl[1][lq][sw + 1] = cvtpk_bf16(pB[2], pB[3]);
    }

    __builtin_amdgcn_s_setprio(1);
    #pragma unroll
    for (int k0g = 0; k0g < 2; ++k0g) {
        const int ch = k0g * 4 + lg;
        const bf16x8 pfA = *(const bf16x8*)&pl[0][lq][(ch ^ (lq & 7)) << 2];
        const bf16x8 pfB = *(const bf16x8*)&pl[1][lq][(ch ^ (lq & 7)) << 2];
        #pragma unroll
        for (int i = 0; i < 4; ++i) {
            otA[i] = __builtin_amdgcn_mfma_f32_16x16x32_bf16(vf[2 * i + k0g], pfA, otA[i], 0, 0, 0);
            otB[i] = __builtin_amdgcn_mfma_f32_16x16x32_bf16(vf[2 * i + k0g], pfB, otB[i], 0, 0, 0);
        }
    }
    __builtin_amdgcn_s_setprio(0);
}

template <int MODE>
__device__ __forceinline__ void attn_body(
    int lbid, const unsigned short* __restrict__ Q,
    const unsigned short* __restrict__ K,
    const unsigned short* __restrict__ Vt,
    unsigned short* __restrict__ Of,
    unsigned int (*plds)[2][16][32], float* __restrict__ psb)
{
    constexpr int H   = (MODE == 0) ? 2 : 8;
    constexpr int M   = (MODE == 0) ? 4096 : 256;
    constexpr int BPB = M / 64;

    const int tid  = threadIdx.x;
    const int lane = tid & 63;
    const int w    = tid >> 6;
    const int lq   = lane & 15;
    const int lg   = lane >> 4;

    const int bh  = lbid / BPB;
    const int qb  = lbid % BPB;
    const int qg  = w & 1;
    const int ks  = w >> 1;
    const int q0g = qb * 64 + qg * 32;
    const int b   = bh / H;
    const int h   = bh % H;

    const unsigned short* qpA = Q + ((size_t)bh * M + q0g + lq) * 64 + 8 * lg;
    const bf16x8 qfA0 = *(const bf16x8*)(qpA);
    const bf16x8 qfA1 = *(const bf16x8*)(qpA + 32);
    const bf16x8 qfB0 = *(const bf16x8*)(qpA + 16 * 64);
    const bf16x8 qfB1 = *(const bf16x8*)(qpA + 16 * 64 + 32);

    const unsigned short* kp = K  + (size_t)b * 65536 + 8 * lane;
    const unsigned short* vp = Vt + (size_t)b * 65536 + 8 * lane;

    f32x4 otA[4], otB[4];
    #pragma unroll
    for (int i = 0; i < 4; ++i) {
        otA[i] = f32x4{0.f, 0.f, 0.f, 0.f};
        otB[i] = f32x4{0.f, 0.f, 0.f, 0.f};
    }
    float psA = 0.f, psB = 0.f;

    const int tb = ks * 8;
    bf16x8 ka[8], kb[8];
    load_ktile(kp, tb, ka);

    #pragma unroll 1
    for (int tt = 0; tt < 4; ++tt) {
        load_ktile(kp, tb + 2 * tt + 1, kb);
        process_tile(tb + 2 * tt, ka, vp, qfA0, qfA1, qfB0, qfB1,
                     otA, otB, psA, psB, plds[w], lq, lg);
        if (tt < 3) load_ktile(kp, tb + 2 * tt + 2, ka);
        process_tile(tb + 2 * tt + 1, kb, vp, qfA0, qfA1, qfB0, qfB1,
                     otA, otB, psA, psB, plds[w], lq, lg);
    }

    __syncthreads();
    float* sc = (float*)plds;
    if (w >= 2) {
        const int off = (w - 2) * 64 + lane;
        #pragma unroll
        for (int i = 0; i < 4; ++i) {
            #pragma unroll
            for (int r = 0; r < 4; ++r) {
                sc[(i * 4 + r) * 128 + off]        = otA[i][r];
                sc[(16 + i * 4 + r) * 128 + off]   = otB[i][r];
            }
        }
        psb[off]       = psA;
        psb[128 + off] = psB;
    }
    __syncthreads();
    if (w < 2) {
        const int off = w * 64 + lane;
        #pragma unroll
        for (int i = 0; i < 4; ++i) {
            #pragma unroll
            for (int r = 0; r < 4; ++r) {
                otA[i][r] += sc[(i * 4 + r) * 128 + off];
                otB[i][r] += sc[(16 + i * 4 + r) * 128 + off];
            }
        }
        psA += psb[off];
        psB += psb[128 + off];

        psA += __shfl_xor(psA, 16); psA += __shfl_xor(psA, 32);
        psB += __shfl_xor(psB, 16); psB += __shfl_xor(psB, 32);
        const float invA = 1.f / psA;
        const float invB = 1.f / psB;

        #pragma unroll
        for (int half = 0; half < 2; ++half) {
            const int   m   = q0g + half * 16 + lq;
            const float inv = half ? invB : invA;
            #pragma unroll
            for (int i = 0; i < 4; ++i) {
                #pragma unroll
                for (int r = 0; r < 4; ++r) {
                    const int   dv  = i * 16 + lg * 4 + r;
                    const float val = (half ? otB[i][r] : otA[i][r]) * inv;
                    size_t dst;
                    if constexpr (MODE == 0) {
                        dst = ((size_t)b * 1024 + (m >> 2)) * 640 + h * 320 + (m & 3) * 64 + dv;
                    } else {
                        dst = ((size_t)b * 1024 + ((h & 3) * 256 + m)) * 640 + (h >> 2) * 320 + 256 + dv;
                    }
                    Of[dst] = f2h(val);
                }
            }
        }
    }
}

__global__ __launch_bounds__(256) void attn_all_k(
    const unsigned short* __restrict__ Q0, const unsigned short* __restrict__ Q2,
    const unsigned short* __restrict__ K, const unsigned short* __restrict__ Vt,
    unsigned short* __restrict__ Of)
{
    __shared__ unsigned int plds[4][2][16][32];
    __shared__ float psb[256];
    if (blockIdx.x < 1024) attn_body<0>(blockIdx.x, Q0, K, Vt, Of, plds, psb);
    else                   attn_body<1>(blockIdx.x - 1024, Q2, K, Vt, Of, plds, psb);
}

// ---------------- final GEMM: single-pass fp16 MFMA, 64x128, 4 waves -------
__global__ __launch_bounds__(256) void out_gemm_f16_k(
    const unsigned short* __restrict__ Of, const unsigned short* __restrict__ WtO,
    float* __restrict__ OUT)
{
    const int tid  = threadIdx.x;
    const int lane = tid & 63;
    const int w    = tid >> 6;
    const int lq   = lane & 15;
    const int lg   = lane >> 4;

    const int bid = blockIdx.x;
    const int rp  = (bid & 7) + 8 * (bid >> 5);   // 0..127 row panel
    const int cb  = (bid >> 3) & 3;               // 0..3 col block

    const long row0    = (long)rp * 64;
    const int  colbase = cb * 128 + w * 32;

    const unsigned short* aP = Of  + (size_t)(row0 + lq) * 640 + lg * 8;
    const unsigned short* bP = WtO + (size_t)(colbase + lq) * 640 + lg * 8;

    f16x8 a0[4], b0[2], a1[4], b1[2];

    auto load0 = [&](int kk) {
        #pragma unroll
        for (int rt = 0; rt < 4; ++rt)
            a0[rt] = *(const f16x8*)(aP + (size_t)rt * 16 * 640 + kk * 32);
        #pragma unroll
        for (int ct = 0; ct < 2; ++ct)
            b0[ct] = *(const f16x8*)(bP + (size_t)ct * 16 * 640 + kk * 32);
    };
    auto load1 = [&](int kk) {
        #pragma unroll
        for (int rt = 0; rt < 4; ++rt)
            a1[rt] = *(const f16x8*)(aP + (size_t)rt * 16 * 640 + kk * 32);
        #pragma unroll
        for (int ct = 0; ct < 2; ++ct)
            b1[ct] = *(const f16x8*)(bP + (size_t)ct * 16 * 640 + kk * 32);
    };

    f32x4 acc[4][2];
    #pragma unroll
    for (int rt = 0; rt < 4; ++rt)
        #pragma unroll
        for (int ct = 0; ct < 2; ++ct) acc[rt][ct] = f32x4{0.f, 0.f, 0.f, 0.f};

    auto mma0 = [&]() {
        #pragma unroll
        for (int rt = 0; rt < 4; ++rt)
            #pragma unroll
            for (int ct = 0; ct < 2; ++ct)
                acc[rt][ct] = __builtin_amdgcn_mfma_f32_16x16x32_f16(a0[rt], b0[ct], acc[rt][ct], 0, 0, 0);
    };
    auto mma1 = [&]() {
        #pragma unroll
        for (int rt = 0; rt < 4; ++rt)
            #pragma unroll
            for (int ct = 0; ct < 2; ++ct)
                acc[rt][ct] = __builtin_amdgcn_mfma_f32_16x16x32_f16(a1[rt], b1[ct], acc[rt][ct], 0, 0, 0);
    };

    load0(0);
    #pragma unroll 1
    for (int kk2 = 0; kk2 < 10; ++kk2) {     // 20 K-chunks, 2 per iter
        load1(2 * kk2 + 1);
        mma0();
        if (kk2 < 9) load0(2 * kk2 + 2);
        mma1();
    }

    #pragma unroll
    for (int rt = 0; rt < 4; ++rt)
        #pragma unroll
        for (int ct = 0; ct < 2; ++ct)
            #pragma unroll
            for (int r = 0; r < 4; ++r)
                OUT[(size_t)(row0 + rt * 16 + lg * 4 + r) * 512
                    + colbase + ct * 16 + lq] = acc[rt][ct][r];
}

extern "C" void kernel_launch(void* const* d_in, const int* in_sizes, int n_in,
                              void* d_out, int out_size, void* d_ws, size_t ws_size,
                              hipStream_t stream) {
    const float* x0   = (const float*)d_in[0];
    const float* x1   = (const float*)d_in[1];
    const float* x2   = (const float*)d_in[2];
    const float* g0   = (const float*)d_in[3];
    const float* b0   = (const float*)d_in[4];
    const float* g1   = (const float*)d_in[5];
    const float* b1   = (const float*)d_in[6];
    const float* g2   = (const float*)d_in[7];
    const float* b2   = (const float*)d_in[8];
    const float* Wq0  = (const float*)d_in[9];
    const float* Wkv  = (const float*)d_in[10];
    const float* Wq2  = (const float*)d_in[11];
    const float* Wout = (const float*)d_in[12];
    float* out = (float*)d_out;

    char* wsb = (char*)d_ws;
    unsigned short* Kf   = (unsigned short*)(wsb + OFFB_KBF);
    unsigned short* Vf   = (unsigned short*)(wsb + OFFB_VT);
    unsigned short* Q0bf = (unsigned short*)(wsb + OFFB_Q0);
    unsigned short* Q2bf = (unsigned short*)(wsb + OFFB_Q2);
    unsigned short* Of   = (unsigned short*)(wsb + OFFB_OF);
    unsigned short* WtKV = (unsigned short*)(wsb + OFFB_WTKV);
    unsigned short* WtQ0 = (unsigned short*)(wsb + OFFB_WTQ0);
    unsigned short* WtQ2 = (unsigned short*)(wsb + OFFB_WTQ2);
    unsigned short* WtO  = (unsigned short*)(wsb + OFFB_WTO);

    transpose_all_k<<<928, 256, 0, stream>>>(Wkv, Wq0, Wq2, Wout,
                                             WtKV, WtQ0, WtQ2, WtO);
    proj_kvq2_k<<<1024, 256, 0, stream>>>(x1, x2, g1, b1, g2, b2,
                                          WtKV, WtQ2, Kf, Vf, Q2bf);
    proj_q0_k<<<2048, 256, 0, stream>>>(x0, g0, b0, WtQ0, Q0bf);
    attn_all_k<<<1280, 256, 0, stream>>>(Q0bf, Q2bf, Kf, Vf, Of);
    out_gemm_f16_k<<<512, 256, 0, stream>>>(Of, WtO, out);
}

// Round 22
// 107.562 us; speedup vs baseline: 1.4844x; 1.1271x over previous
//
#include <hip/hip_runtime.h>

// ---------------------------------------------------------------------------
// Attention3: B=8, NKV=1024, D0=256, D1=512, D2=1024, DH=64, H0=2, H2=8
// Round 21 (base = R17/R20 best-known 121.2 us):
//  1) softmax scale folded into Q projections (Q stored pre-scaled by
//     0.125*log2e; K/V scale=1.0 bitwise no-op) -> attn exp2(S) directly.
//  2) out_gemm: A-panel staged cooperatively in LDS (double-buffered
//     As[2][64][40] fp16, padded; 1 coalesced load/thread/chunk) -> A read
//     once per block instead of 4x; per-wave global loads 6 -> 3 per chunk.
// Everything else identical to R20 (verified, absmax 2.441e-4).
//
// ws layout (BYTE offsets):
//   Kf   [8][16][4][2][64][8] bf16 @ 0 MB   (1 MB)
//   Vf   [8][16][4][2][64][8] bf16 @ 1 MB   (1 MB)
//   Q0bf [16][4096][64] bf16 @ 2 MB   (8 MB)   (pre-scaled)
//   Q2bf [64][256][64]  bf16 @ 10 MB  (2 MB)   (pre-scaled)
//   Of   [8192][640]    fp16 @ 12 MB  (10.5 MB)
//   WtKV [128][512]     bf16 @ 34 MB
//   WtQ0 [128][256]     bf16 @ 35 MB
//   WtQ2 [512][1024]    bf16 @ 36 MB  (1 MB)
//   WtO  [512][640]     fp16 @ 37 MB
// ---------------------------------------------------------------------------

typedef __attribute__((ext_vector_type(8))) short bf16x8;
typedef __attribute__((ext_vector_type(8))) _Float16 f16x8;
typedef __attribute__((ext_vector_type(4))) float f32x4;

constexpr size_t OFFB_KBF  = 0;
constexpr size_t OFFB_VT   = (size_t)1 << 20;
constexpr size_t OFFB_Q0   = (size_t)2 << 20;
constexpr size_t OFFB_Q2   = (size_t)10 << 20;
constexpr size_t OFFB_OF   = (size_t)12 << 20;
constexpr size_t OFFB_WTKV = (size_t)34 << 20;
constexpr size_t OFFB_WTQ0 = (size_t)35 << 20;
constexpr size_t OFFB_WTQ2 = (size_t)36 << 20;
constexpr size_t OFFB_WTO  = (size_t)37 << 20;

__device__ __forceinline__ unsigned short f2bf(float f) {
    union { float f; unsigned int u; } x; x.f = f;
    const unsigned int r = x.u + 0x7fffu + ((x.u >> 16) & 1u);
    return (unsigned short)(r >> 16);
}
__device__ __forceinline__ unsigned short f2h(float f) {
    union { _Float16 h; unsigned short u; } x;
    x.h = (_Float16)f;
    return x.u;
}
__device__ __forceinline__ unsigned int cvtpk_bf16(float lo, float hi) {
    unsigned int r;
    asm("v_cvt_pk_bf16_f32 %0, %1, %2" : "=v"(r) : "v"(lo), "v"(hi));
    return r;
}
__device__ __forceinline__ float fexp2(float x) {
    float r;
    asm("v_exp_f32 %0, %1" : "=v"(r) : "v"(x));
    return r;
}
// 0.125 (attn scale) * log2(e), folded into Q projection outputs
#define EXP2_SCALE 0.18033688011112042f

// ---------------- merged weight transpose+convert ---------------------------
template <int R, int C, bool F16>
__device__ __forceinline__ void transpose_w_body(
    int lbid, const float* __restrict__ W,
    unsigned short* __restrict__ D, float (*t)[33])
{
    const int tid = threadIdx.x;
    const int tx = tid & 31, ty = tid >> 5;
    const int bx = lbid % (C / 32);
    const int by = lbid / (C / 32);
    #pragma unroll
    for (int j = 0; j < 4; ++j) {
        const int r = ty + j * 8;
        t[r][tx] = W[(size_t)(by * 32 + r) * C + bx * 32 + tx];
    }
    __syncthreads();
    #pragma unroll
    for (int j = 0; j < 4; ++j) {
        const int r = ty + j * 8;
        const float v = t[tx][r];
        const size_t dst = (size_t)(bx * 32 + r) * R + by * 32 + tx;
        D[dst] = F16 ? f2h(v) : f2bf(v);
    }
}

__global__ __launch_bounds__(256) void transpose_all_k(
    const float* __restrict__ Wkv, const float* __restrict__ Wq0,
    const float* __restrict__ Wq2, const float* __restrict__ Wout,
    unsigned short* __restrict__ WtKV, unsigned short* __restrict__ WtQ0,
    unsigned short* __restrict__ WtQ2, unsigned short* __restrict__ WtO)
{
    __shared__ float t[32][33];
    const int b = blockIdx.x;
    if (b < 64)       transpose_w_body<512, 128, false>(b, Wkv, WtKV, t);
    else if (b < 96)  transpose_w_body<256, 128, false>(b - 64, Wq0, WtQ0, t);
    else if (b < 608) transpose_w_body<1024, 512, false>(b - 96, Wq2, WtQ2, t);
    else              transpose_w_body<640, 512, true>(b - 608, Wout, WtO, t);
}

// ---------------- LN + MFMA projection body (R14 math + output scale SC) ----
// SC = 1.0f for K/V (bitwise no-op), EXP2_SCALE for Q0/Q2.
template <int D, int MODE, int NRB>
__device__ __forceinline__ void ln_proj_body(
    int lbid, const float* __restrict__ X, const float* __restrict__ G,
    const float* __restrict__ Bv, const unsigned short* __restrict__ Wt,
    unsigned short* __restrict__ O0, unsigned short* __restrict__ O1,
    unsigned int* xn, float SC)
{
    constexpr int NJ = D / 128;

    const int tid  = threadIdx.x;
    const int lane = tid & 63;
    const int w    = tid >> 6;
    const int lq   = lane & 15;
    const int lg   = lane >> 4;

    const int rb      = lbid % NRB;
    const int cb      = lbid / NRB;
    const int colbase = cb * 128 + w * 32;

    #pragma unroll
    for (int rr = 0; rr < 4; ++rr) {
        const int r = w * 4 + rr;
        const float* xp = X + ((size_t)rb * 16 + r) * D;
        float2 xv[NJ];
        float ps = 0.f, pq = 0.f;
        #pragma unroll
        for (int j = 0; j < NJ; ++j) {
            xv[j] = *(const float2*)&xp[2 * lane + 128 * j];
            ps += xv[j].x + xv[j].y;
            pq += xv[j].x * xv[j].x + xv[j].y * xv[j].y;
        }
        #pragma unroll
        for (int off = 32; off >= 1; off >>= 1) {
            ps += __shfl_xor(ps, off);
            pq += __shfl_xor(pq, off);
        }
        const float mu  = ps * (1.f / D);
        const float var = pq * (1.f / D) - mu * mu;
        const float rs  = rsqrtf(var + 1e-5f);
        #pragma unroll
        for (int j = 0; j < NJ; ++j) {
            const int i2 = 2 * lane + 128 * j;
            const float2 gv = *(const float2*)&G[i2];
            const float2 bv = *(const float2*)&Bv[i2];
            const float a = (xv[j].x - mu) * rs * gv.x + bv.x;
            const float c = (xv[j].y - mu) * rs * gv.y + bv.y;
            const int pi = lane + 64 * j;
            xn[r * (D / 2) + ((((pi >> 2) ^ (r & 7)) << 2) | (pi & 3))] =
                cvtpk_bf16(a, c);
        }
    }
    __syncthreads();

    const unsigned short* wp = Wt + (size_t)(colbase + lq) * D + lg * 8;
    f32x4 acc0 = f32x4{0.f, 0.f, 0.f, 0.f};
    f32x4 acc1 = f32x4{0.f, 0.f, 0.f, 0.f};
    #pragma unroll 4
    for (int kk = 0; kk < D / 32; ++kk) {
        const int ch = (kk * 4 + lg) ^ (lq & 7);
        const bf16x8 xf = *(const bf16x8*)&xn[lq * (D / 2) + ch * 4];
        const bf16x8 wf0 = *(const bf16x8*)(wp + kk * 32);
        const bf16x8 wf1 = *(const bf16x8*)(wp + 16 * D + kk * 32);
        acc0 = __builtin_amdgcn_mfma_f32_16x16x32_bf16(wf0, xf, acc0, 0, 0, 0);
        acc1 = __builtin_amdgcn_mfma_f32_16x16x32_bf16(wf1, xf, acc1, 0, 0, 0);
    }

    const long grow = (long)rb * 16 + lq;
    #pragma unroll
    for (int t = 0; t < 2; ++t) {
        const f32x4 acc = t ? acc1 : acc0;
        #pragma unroll
        for (int r = 0; r < 4; ++r) {
            const int c = colbase + t * 16 + lg * 4 + r;
            const unsigned short a = f2bf(acc[r] * SC);
            if constexpr (MODE == 0) {
                const long bb   = grow >> 10;
                const long keyb = grow & 1023;
                const long tt_  = keyb >> 6;
                if (c < 64) {
                    const int kt = (int)((keyb >> 4) & 3);
                    const int ch = c >> 5;
                    const int ln = (int)((keyb & 15) | (((c & 31) >> 3) << 4));
                    const int e  = c & 7;
                    O0[((((bb * 16 + tt_) * 4 + kt) * 2 + ch) * 64 + ln) * 8 + e] = a;
                } else {
                    const int dv = c - 64;
                    const int i  = dv >> 4;
                    const int ch = (int)((keyb & 63) >> 5);
                    const int ln = (int)((dv & 15) | (((keyb & 31) >> 3) << 4));
                    const int e  = (int)(keyb & 7);
                    O1[((((bb * 16 + tt_) * 4 + i) * 2 + ch) * 64 + ln) * 8 + e] = a;
                }
            } else if constexpr (MODE == 1) {
                const long b = grow >> 12;
                const long m = grow & 4095;
                const int  h = c >> 6, dd = c & 63;
                O0[(((b * 2 + h) << 12) + m) * 64 + dd] = a;
            } else {
                const long b = grow >> 8;
                const long m = grow & 255;
                const int  h = c >> 6, dd = c & 63;
                O0[(((b * 8 + h) << 8) + m) * 64 + dd] = a;
            }
        }
    }
}

__global__ __launch_bounds__(256) void proj_kvq2_k(
    const float* __restrict__ x1, const float* __restrict__ x2,
    const float* __restrict__ g1, const float* __restrict__ b1,
    const float* __restrict__ g2, const float* __restrict__ b2,
    const unsigned short* __restrict__ WtKV, const unsigned short* __restrict__ WtQ2,
    unsigned short* __restrict__ Kf, unsigned short* __restrict__ Vf,
    unsigned short* __restrict__ Q2bf)
{
    __shared__ unsigned int xn[8192];
    const int b = blockIdx.x;
    if (b < 512) ln_proj_body<512, 0, 512>(b, x1, g1, b1, WtKV, Kf, Vf, xn, 1.0f);
    else         ln_proj_body<1024, 2, 128>(b - 512, x2, g2, b2, WtQ2, Q2bf, nullptr, xn, EXP2_SCALE);
}

__global__ __launch_bounds__(256) void proj_q0_k(
    const float* __restrict__ x0,
    const float* __restrict__ g0, const float* __restrict__ b0,
    const unsigned short* __restrict__ WtQ0,
    unsigned short* __restrict__ Q0bf)
{
    __shared__ unsigned int xn[2048];
    ln_proj_body<256, 1, 2048>(blockIdx.x, x0, g0, b0, WtQ0, Q0bf, nullptr, xn, EXP2_SCALE);
}

// ---------------- MFMA attention (fragment K/V, 2-way key-split) ------------
__device__ __forceinline__ void load_ktile(
    const unsigned short* __restrict__ kp, int t, bf16x8 (&kf)[8])
{
    const unsigned short* ktb = kp + (size_t)t * 8 * 512;
    #pragma unroll
    for (int kt = 0; kt < 4; ++kt) {
        kf[2 * kt]     = *(const bf16x8*)(ktb + (kt * 2 + 0) * 512);
        kf[2 * kt + 1] = *(const bf16x8*)(ktb + (kt * 2 + 1) * 512);
    }
}

__device__ __forceinline__ void process_tile(
    int t, const bf16x8 (&kf)[8],
    const unsigned short* __restrict__ vp,
    const bf16x8& qfA0, const bf16x8& qfA1,
    const bf16x8& qfB0, const bf16x8& qfB1,
    f32x4 (&otA)[4], f32x4 (&otB)[4], float& psA, float& psB,
    unsigned int (&pl)[2][16][32], int lq, int lg)
{
    const unsigned short* vtb = vp + (size_t)t * 8 * 512;
    bf16x8 vf[8];
    #pragma unroll
    for (int i = 0; i < 4; ++i) {
        vf[2 * i]     = *(const bf16x8*)(vtb + (i * 2 + 0) * 512);
        vf[2 * i + 1] = *(const bf16x8*)(vtb + (i * 2 + 1) * 512);
    }

    #pragma unroll
    for (int kt = 0; kt < 4; ++kt) {
        f32x4 sA = f32x4{0.f, 0.f, 0.f, 0.f};
        sA = __builtin_amdgcn_mfma_f32_16x16x32_bf16(kf[2 * kt], qfA0, sA, 0, 0, 0);
        sA = __builtin_amdgcn_mfma_f32_16x16x32_bf16(kf[2 * kt + 1], qfA1, sA, 0, 0, 0);
        f32x4 sB = f32x4{0.f, 0.f, 0.f, 0.f};
        sB = __builtin_amdgcn_mfma_f32_16x16x32_bf16(kf[2 * kt], qfB0, sB, 0, 0, 0);
        sB = __builtin_amdgcn_mfma_f32_16x16x32_bf16(kf[2 * kt + 1], qfB1, sB, 0, 0, 0);

        // Q pre-scaled by 0.125*log2(e) at projection -> exp2 directly
        float pA[4], pB[4];
        #pragma unroll
        for (int r = 0; r < 4; ++r) {
            pA[r] = fexp2(sA[r]);
            pB[r] = fexp2(sB[r]);
            psA += pA[r];
            psB += pB[r];
        }
        const int sw = (((2 * kt + (lg >> 1)) ^ (lq & 7)) << 2) | (2 * (lg & 1));
        pl[0][lq][sw]     = cvtpk_bf16(pA[0], pA[1]);
        pl[0][lq][sw + 1] = cvtpk_bf16(pA[2], pA[3]);
        pl[1][lq][sw]     = cvtpk_bf16(pB[0], pB[1]);
        pl[1][lq][sw + 1] = cvtpk_bf16(pB[2], pB[3]);
    }

    __builtin_amdgcn_s_setprio(1);
    #pragma unroll
    for (int k0g = 0; k0g < 2; ++k0g) {
        const int ch = k0g * 4 + lg;
        const bf16x8 pfA = *(const bf16x8*)&pl[0][lq][(ch ^ (lq & 7)) << 2];
        const bf16x8 pfB = *(const bf16x8*)&pl[1][lq][(ch ^ (lq & 7)) << 2];
        #pragma unroll
        for (int i = 0; i < 4; ++i) {
            otA[i] = __builtin_amdgcn_mfma_f32_16x16x32_bf16(vf[2 * i + k0g], pfA, otA[i], 0, 0, 0);
            otB[i] = __builtin_amdgcn_mfma_f32_16x16x32_bf16(vf[2 * i + k0g], pfB, otB[i], 0, 0, 0);
        }
    }
    __builtin_amdgcn_s_setprio(0);
}

template <int MODE>
__device__ __forceinline__ void attn_body(
    int lbid, const unsigned short* __restrict__ Q,
    const unsigned short* __restrict__ K,
    const unsigned short* __restrict__ Vt,
    unsigned short* __restrict__ Of,
    unsigned int (*plds)[2][16][32], float* __restrict__ psb)
{
    constexpr int H   = (MODE == 0) ? 2 : 8;
    constexpr int M   = (MODE == 0) ? 4096 : 256;
    constexpr int BPB = M / 64;

    const int tid  = threadIdx.x;
    const int lane = tid & 63;
    const int w    = tid >> 6;
    const int lq   = lane & 15;
    const int lg   = lane >> 4;

    const int bh  = lbid / BPB;
    const int qb  = lbid % BPB;
    const int qg  = w & 1;
    const int ks  = w >> 1;
    const int q0g = qb * 64 + qg * 32;
    const int b   = bh / H;
    const int h   = bh % H;

    const unsigned short* qpA = Q + ((size_t)bh * M + q0g + lq) * 64 + 8 * lg;
    const bf16x8 qfA0 = *(const bf16x8*)(qpA);
    const bf16x8 qfA1 = *(const bf16x8*)(qpA + 32);
    const bf16x8 qfB0 = *(const bf16x8*)(qpA + 16 * 64);
    const bf16x8 qfB1 = *(const bf16x8*)(qpA + 16 * 64 + 32);

    const unsigned short* kp = K  + (size_t)b * 65536 + 8 * lane;
    const unsigned short* vp = Vt + (size_t)b * 65536 + 8 * lane;

    f32x4 otA[4], otB[4];
    #pragma unroll
    for (int i = 0; i < 4; ++i) {
        otA[i] = f32x4{0.f, 0.f, 0.f, 0.f};
        otB[i] = f32x4{0.f, 0.f, 0.f, 0.f};
    }
    float psA = 0.f, psB = 0.f;

    const int tb = ks * 8;
    bf16x8 ka[8], kb[8];
    load_ktile(kp, tb, ka);

    #pragma unroll 1
    for (int tt = 0; tt < 4; ++tt) {
        load_ktile(kp, tb + 2 * tt + 1, kb);
        process_tile(tb + 2 * tt, ka, vp, qfA0, qfA1, qfB0, qfB1,
                     otA, otB, psA, psB, plds[w], lq, lg);
        if (tt < 3) load_ktile(kp, tb + 2 * tt + 2, ka);
        process_tile(tb + 2 * tt + 1, kb, vp, qfA0, qfA1, qfB0, qfB1,
                     otA, otB, psA, psB, plds[w], lq, lg);
    }

    __syncthreads();
    float* sc = (float*)plds;
    if (w >= 2) {
        const int off = (w - 2) * 64 + lane;
        #pragma unroll
        for (int i = 0; i < 4; ++i) {
            #pragma unroll
            for (int r = 0; r < 4; ++r) {
                sc[(i * 4 + r) * 128 + off]        = otA[i][r];
                sc[(16 + i * 4 + r) * 128 + off]   = otB[i][r];
            }
        }
        psb[off]       = psA;
        psb[128 + off] = psB;
    }
    __syncthreads();
    if (w < 2) {
        const int off = w * 64 + lane;
        #pragma unroll
        for (int i = 0; i < 4; ++i) {
            #pragma unroll
            for (int r = 0; r < 4; ++r) {
                otA[i][r] += sc[(i * 4 + r) * 128 + off];
                otB[i][r] += sc[(16 + i * 4 + r) * 128 + off];
            }
        }
        psA += psb[off];
        psB += psb[128 + off];

        psA += __shfl_xor(psA, 16); psA += __shfl_xor(psA, 32);
        psB += __shfl_xor(psB, 16); psB += __shfl_xor(psB, 32);
        const float invA = 1.f / psA;
        const float invB = 1.f / psB;

        #pragma unroll
        for (int half = 0; half < 2; ++half) {
            const int   m   = q0g + half * 16 + lq;
            const float inv = half ? invB : invA;
            #pragma unroll
            for (int i = 0; i < 4; ++i) {
                #pragma unroll
                for (int r = 0; r < 4; ++r) {
                    const int   dv  = i * 16 + lg * 4 + r;
                    const float val = (half ? otB[i][r] : otA[i][r]) * inv;
                    size_t dst;
                    if constexpr (MODE == 0) {
                        dst = ((size_t)b * 1024 + (m >> 2)) * 640 + h * 320 + (m & 3) * 64 + dv;
                    } else {
                        dst = ((size_t)b * 1024 + ((h & 3) * 256 + m)) * 640 + (h >> 2) * 320 + 256 + dv;
                    }
                    Of[dst] = f2h(val);
                }
            }
        }
    }
}

__global__ __launch_bounds__(256) void attn_all_k(
    const unsigned short* __restrict__ Q0, const unsigned short* __restrict__ Q2,
    const unsigned short* __restrict__ K, const unsigned short* __restrict__ Vt,
    unsigned short* __restrict__ Of)
{
    __shared__ unsigned int plds[4][2][16][32];
    __shared__ float psb[256];
    if (blockIdx.x < 1024) attn_body<0>(blockIdx.x, Q0, K, Vt, Of, plds, psb);
    else                   attn_body<1>(blockIdx.x - 1024, Q2, K, Vt, Of, plds, psb);
}

// ---------------- final GEMM: fp16 MFMA, 64x128, LDS-staged A panel ---------
// A panel (64 rows x 32 k per chunk) staged once per block into double-
// buffered As[2][64][40] (pad -> 2-way bank alias = free); all 4 waves read
// fragments from LDS. Per-wave global loads per chunk: 1 (stage) + 2 (B).
// XCD map: rp=(bid&7)+8*(bid>>5), cb=(bid>>3)&3.
__global__ __launch_bounds__(256) void out_gemm_f16_k(
    const unsigned short* __restrict__ Of, const unsigned short* __restrict__ WtO,
    float* __restrict__ OUT)
{
    __shared__ __align__(16) unsigned short As[2][64][40];  // 10.24 KB

    const int tid  = threadIdx.x;
    const int lane = tid & 63;
    const int w    = tid >> 6;
    const int lq   = lane & 15;
    const int lg   = lane >> 4;

    const int bid = blockIdx.x;
    const int rp  = (bid & 7) + 8 * (bid >> 5);   // 0..127 row panel
    const int cb  = (bid >> 3) & 3;               // 0..3 col block

    const long row0    = (long)rp * 64;
    const int  colbase = cb * 128 + w * 32;

    const int srow = tid >> 2;          // 0..63
    const int sko  = (tid & 3) * 8;     // 0,8,16,24
    const unsigned short* aSrc = Of  + (size_t)(row0 + srow) * 640 + sko;
    const unsigned short* bP   = WtO + (size_t)(colbase + lq) * 640 + lg * 8;

    f16x8 b0[2], b1[2];

    auto stage = [&](int kk, int buf) {
        *(f16x8*)&As[buf][srow][sko] = *(const f16x8*)(aSrc + kk * 32);
    };
    auto loadB0 = [&](int kk) {
        b0[0] = *(const f16x8*)(bP + kk * 32);
        b0[1] = *(const f16x8*)(bP + 16 * 640 + kk * 32);
    };
    auto loadB1 = [&](int kk) {
        b1[0] = *(const f16x8*)(bP + kk * 32);
        b1[1] = *(const f16x8*)(bP + 16 * 640 + kk * 32);
    };

    f32x4 acc[4][2];
    #pragma unroll
    for (int rt = 0; rt < 4; ++rt)
        #pragma unroll
        for (int ct = 0; ct < 2; ++ct) acc[rt][ct] = f32x4{0.f, 0.f, 0.f, 0.f};

    auto mmaWith = [&](int buf, f16x8 (&bb)[2]) {
        f16x8 a[4];
        #pragma unroll
        for (int rt = 0; rt < 4; ++rt)
            a[rt] = *(const f16x8*)&As[buf][rt * 16 + lq][lg * 8];
        #pragma unroll
        for (int rt = 0; rt < 4; ++rt)
            #pragma unroll
            for (int ct = 0; ct < 2; ++ct)
                acc[rt][ct] = __builtin_amdgcn_mfma_f32_16x16x32_f16(a[rt], bb[ct], acc[rt][ct], 0, 0, 0);
    };

    stage(0, 0);
    loadB0(0);
    __syncthreads();

    #pragma unroll 1
    for (int it = 0; it < 10; ++it) {
        const int kk = 2 * it;
        stage(kk + 1, 1);                 // fill buf1 while buf0 consumed
        loadB1(kk + 1);
        mmaWith(0, b0);
        __syncthreads();                  // buf0 reads done; buf1 writes visible
        if (it < 9) { stage(kk + 2, 0); loadB0(kk + 2); }
        mmaWith(1, b1);
        __syncthreads();                  // buf1 reads done; buf0 writes visible
    }

    #pragma unroll
    for (int rt = 0; rt < 4; ++rt)
        #pragma unroll
        for (int ct = 0; ct < 2; ++ct)
            #pragma unroll
            for (int r = 0; r < 4; ++r)
                OUT[(size_t)(row0 + rt * 16 + lg * 4 + r) * 512
                    + colbase + ct * 16 + lq] = acc[rt][ct][r];
}

extern "C" void kernel_launch(void* const* d_in, const int* in_sizes, int n_in,
                              void* d_out, int out_size, void* d_ws, size_t ws_size,
                              hipStream_t stream) {
    const float* x0   = (const float*)d_in[0];
    const float* x1   = (const float*)d_in[1];
    const float* x2   = (const float*)d_in[2];
    const float* g0   = (const float*)d_in[3];
    const float* b0   = (const float*)d_in[4];
    const float* g1   = (const float*)d_in[5];
    const float* b1   = (const float*)d_in[6];
    const float* g2   = (const float*)d_in[7];
    const float* b2   = (const float*)d_in[8];
    const float* Wq0  = (const float*)d_in[9];
    const float* Wkv  = (const float*)d_in[10];
    const float* Wq2  = (const float*)d_in[11];
    const float* Wout = (const float*)d_in[12];
    float* out = (float*)d_out;

    char* wsb = (char*)d_ws;
    unsigned short* Kf   = (unsigned short*)(wsb + OFFB_KBF);
    unsigned short* Vf   = (unsigned short*)(wsb + OFFB_VT);
    unsigned short* Q0bf = (unsigned short*)(wsb + OFFB_Q0);
    unsigned short* Q2bf = (unsigned short*)(wsb + OFFB_Q2);
    unsigned short* Of   = (unsigned short*)(wsb + OFFB_OF);
    unsigned short* WtKV = (unsigned short*)(wsb + OFFB_WTKV);
    unsigned short* WtQ0 = (unsigned short*)(wsb + OFFB_WTQ0);
    unsigned short* WtQ2 = (unsigned short*)(wsb + OFFB_WTQ2);
    unsigned short* WtO  = (unsigned short*)(wsb + OFFB_WTO);

    transpose_all_k<<<928, 256, 0, stream>>>(Wkv, Wq0, Wq2, Wout,
                                             WtKV, WtQ0, WtQ2, WtO);
    proj_kvq2_k<<<1024, 256, 0, stream>>>(x1, x2, g1, b1, g2, b2,
                                          WtKV, WtQ2, Kf, Vf, Q2bf);
    proj_q0_k<<<2048, 256, 0, stream>>>(x0, g0, b0, WtQ0, Q0bf);
    attn_all_k<<<1280, 256, 0, stream>>>(Q0bf, Q2bf, Kf, Vf, Of);
    out_gemm_f16_k<<<512, 256, 0, stream>>>(Of, WtO, out);
}